// Round 18
// baseline (277.721 us; speedup 1.0000x reference)
//
#include <hip/hip_runtime.h>

#define B_ 8
#define S_ 2048
#define IN_ 4096
#define OUT_ 4096
#define R_ 16
#define E_ 64

typedef float v4f __attribute__((ext_vector_type(4)));

__device__ __forceinline__ float4 ntload4(const float* p) {
  v4f t = __builtin_nontemporal_load((const v4f*)p);
  float4 r; r.x = t.x; r.y = t.y; r.z = t.z; r.w = t.w; return r;
}
__device__ __forceinline__ void ntstore4(float* p, float4 v) {
  v4f t; t.x = v.x; t.y = v.y; t.z = v.z; t.w = v.w;
  __builtin_nontemporal_store(t, (v4f*)p);
}

__device__ __forceinline__ float dot4(float4 a, float4 b) {
  return a.x*b.x + a.y*b.y + a.z*b.z + a.w*b.w;
}

// wave-parallel top-16 (descending, ties -> lower index, matching lax.top_k)
__device__ __forceinline__ void topk16(float v, int* __restrict__ dst) {
  const int lane = threadIdx.x & 63;
  for (int r = 0; r < R_; ++r) {
    float mv = v; int mi = lane;
    #pragma unroll
    for (int off = 1; off < 64; off <<= 1) {
      float v2 = __shfl_xor(mv, off, 64);
      int   i2 = __shfl_xor(mi, off, 64);
      if (v2 > mv || (v2 == mv && i2 < mi)) { mv = v2; mi = i2; }
    }
    if (lane == 0) dst[r] = mi;
    if (lane == mi) v = -__builtin_inff();
  }
}

// ---------------- K1: score partial dots (256 blocks = b x eg x ic) ----------
__global__ __launch_bounds__(256) void k_scores(
    const float* __restrict__ q, const float* __restrict__ W_rA,
    const float* __restrict__ W_rB, float* __restrict__ sApart,
    float* __restrict__ gApart)
{
  const int bx = blockIdx.x;
  const int b = bx >> 5, eg = (bx >> 2) & 7, ic = bx & 3;
  __shared__ float qs[1024];
  const int tid = threadIdx.x;
  {
    const float4* q4 = (const float4*)(q + (size_t)b * IN_ + ic * 1024);
    ((float4*)qs)[tid] = q4[tid];
  }
  __syncthreads();
  const int wave = tid >> 6, lane = tid & 63;
  const float4* qs4 = (const float4*)qs;
  #pragma unroll
  for (int k = 0; k < 2; ++k) {
    const int e = eg * 8 + wave * 2 + k;
    const float4* wa = (const float4*)(W_rA + (size_t)e * IN_ + ic * 1024);
    const float4* wb = (const float4*)(W_rB + (size_t)e * IN_ + ic * 1024);
    float pa = 0.f, pb = 0.f;
    #pragma unroll
    for (int i = 0; i < 4; ++i) {
      float4 qv = qs4[lane + i * 64];
      pa += dot4(qv, wa[lane + i * 64]);
      pb += dot4(qv, wb[lane + i * 64]);
    }
    #pragma unroll
    for (int off = 1; off < 64; off <<= 1) {
      pa += __shfl_xor(pa, off, 64);
      pb += __shfl_xor(pb, off, 64);
    }
    if (lane == 0) {
      sApart[(ic * B_ + b) * E_ + e] = pa;
      gApart[(ic * B_ + b) * E_ + e] = pb;
    }
  }
}

// ---------------- K1b: reduce partials, bias, topk_A, final gB0 --------------
__global__ __launch_bounds__(64) void k_topk_a(
    const float* __restrict__ sApart, const float* __restrict__ gApart,
    const float* __restrict__ b_rA, const float* __restrict__ b_rB,
    float* __restrict__ gB0, int* __restrict__ idxA)
{
  const int b = blockIdx.x;
  const int e = threadIdx.x & 63;
  float sA = b_rA[e], g = b_rB[e];
  #pragma unroll
  for (int ic = 0; ic < 4; ++ic) {
    sA += sApart[(ic * B_ + b) * E_ + e];
    g  += gApart[(ic * B_ + b) * E_ + e];
  }
  gB0[b * E_ + e] = g;
  topk16(sA, idxA + b * R_);
}

// ---------------- K2: fused [cfs (blocks 0-127) | after_A (blocks 128-2175)] --
// R11 semantics; LDS trimmed 36 -> 32 KB (aa aliases As after a barrier) and
// __launch_bounds__(256,5) caps VGPR at ~102 -> 5 blocks/CU (was 4).
__global__ __launch_bounds__(256, 5) void k_fused_ac(
    const float* __restrict__ x, const float* __restrict__ A_pool,
    const int* __restrict__ idxA, const float* __restrict__ cfs,
    float* __restrict__ gBpart, float* __restrict__ partial)
{
  __shared__ union {
    struct { float4 As[R_][128]; } a;                      // 32 KB
    struct { float as[B_][512]; float red[4][B_][E_]; } c; // 24.5 KB
  } sm;
  const int tid = threadIdx.x;

  if (blockIdx.x < 128) {
    // ---------------- cfs einsum partials (R11 body) ----------------
    const int blk = blockIdx.x;
    const int r = blk >> 3, ic = blk & 7;
    {
      const int b = tid >> 5, t = tid & 31;
      const int e = idxA[b * R_ + r];
      const float4* src = (const float4*)(A_pool + ((size_t)e * R_ + r) * IN_ + ic * 512);
      float4* dst = (float4*)sm.c.as[b];
      for (int j = t; j < 128; j += 32) dst[j] = src[j];
    }
    __syncthreads();
    const int e = tid & 63, part = tid >> 6;
    float acc[B_];
    #pragma unroll
    for (int b = 0; b < B_; ++b) acc[b] = 0.f;
    const float* cbase = cfs + ((size_t)r * IN_ + ic * 512) * E_ + e;
    for (int i = part * 128; i < part * 128 + 128; ++i) {
      float c = __builtin_nontemporal_load(cbase + (size_t)i * E_);
      #pragma unroll
      for (int b = 0; b < B_; ++b) acc[b] += sm.c.as[b][i] * c;
    }
    #pragma unroll
    for (int b = 0; b < B_; ++b) sm.c.red[part][b][e] = acc[b];
    __syncthreads();
    if (tid < 64) {
      #pragma unroll
      for (int b = 0; b < B_; ++b)
        gBpart[((size_t)blk * B_ + b) * E_ + tid] =
            sm.c.red[0][b][tid] + sm.c.red[1][b][tid] +
            sm.c.red[2][b][tid] + sm.c.red[3][b][tid];
    }
    return;
  }

  // ---------------- after_A split-K (R9/R11 proven body) ----------------
  const int bx = blockIdx.x - 128;
  const int rt = bx & 31, b = (bx >> 5) & 7, ks = bx >> 8;
  const int row0 = rt * 64;
  {
    const int sr = tid >> 4, st = tid & 15;
    const float4* src =
        (const float4*)(A_pool + ((size_t)idxA[b * R_ + sr] * R_ + sr) * IN_ + ks * 512);
    #pragma unroll
    for (int j = st; j < 128; j += 16) sm.a.As[sr][j] = src[j];
  }
  const int rg = tid >> 4, p = tid & 15;  // rows rg*4..rg*4+3, 16-way i4 split
  const float* xbase = x + ((size_t)b * S_ + row0 + rg * 4) * IN_ + ks * 512;
  float acc[4][R_];
  #pragma unroll
  for (int m = 0; m < 4; ++m)
    #pragma unroll
    for (int r = 0; r < R_; ++r) acc[m][r] = 0.f;
  __syncthreads();

  #pragma unroll 2
  for (int step = 0; step < 8; ++step) {
    const int i4 = step * 16 + p;
    float4 xv[4];
    #pragma unroll
    for (int m = 0; m < 4; ++m)
      xv[m] = ntload4(xbase + (size_t)m * IN_ + i4 * 4);
    #pragma unroll
    for (int r = 0; r < R_; ++r) {
      float4 a = sm.a.As[r][i4];
      #pragma unroll
      for (int m = 0; m < 4; ++m) acc[m][r] += dot4(xv[m], a);
    }
  }
  // reduce across the 16 p-lanes (bits 0..3 of lane)
  #pragma unroll
  for (int m = 0; m < 4; ++m)
    #pragma unroll
    for (int r = 0; r < R_; ++r) {
      float v = acc[m][r];
      v += __shfl_xor(v, 1, 64);
      v += __shfl_xor(v, 2, 64);
      v += __shfl_xor(v, 4, 64);
      v += __shfl_xor(v, 8, 64);
      acc[m][r] = v;
    }
  // aa aliases the start of As (first 4 KB); all As reads are complete only
  // after this barrier, so the alias is race-free.
  __syncthreads();
  float* aa = (float*)&sm.a.As[0][0];   // [64][R_] staging
  if (p == 0) {
    #pragma unroll
    for (int m = 0; m < 4; ++m) {
      float4* d4 = (float4*)(aa + (rg * 4 + m) * R_);
      d4[0] = make_float4(acc[m][0],  acc[m][1],  acc[m][2],  acc[m][3]);
      d4[1] = make_float4(acc[m][4],  acc[m][5],  acc[m][6],  acc[m][7]);
      d4[2] = make_float4(acc[m][8],  acc[m][9],  acc[m][10], acc[m][11]);
      d4[3] = make_float4(acc[m][12], acc[m][13], acc[m][14], acc[m][15]);
    }
  }
  __syncthreads();
  // coalesced nt 4 KB tile store
  float4 w = ((const float4*)aa)[tid];
  ntstore4(partial + (((size_t)(b * 32 + rt) * 8 + ks) << 10) + tid * 4, w);
}

// ---------------- K3: topk_B + pack lora_B fused ------------------------------
// grid 128 = b(8) x r(16). Wave-split reduction over 128 gBpart blocks.
__global__ __launch_bounds__(256) void k_topkb_pack(
    const float* __restrict__ gB0, const float* __restrict__ gBpart,
    const float* __restrict__ B_pool, float* __restrict__ loraBp)
{
  const int b = blockIdx.x >> 4, r = blockIdx.x & 15;
  __shared__ float red[4][E_];
  __shared__ int idxB_s[R_];
  const int tid = threadIdx.x;
  const int wave = tid >> 6, lane = tid & 63;
  float p = 0.f;
  for (int blk = wave * 32; blk < wave * 32 + 32; ++blk)
    p += gBpart[((size_t)blk * B_ + b) * E_ + lane];
  red[wave][lane] = p;
  __syncthreads();
  if (wave == 0) {
    float v = gB0[b * E_ + lane] + red[0][lane] + red[1][lane] + red[2][lane] + red[3][lane];
    topk16(v, idxB_s);
  }
  __syncthreads();
  const int e = idxB_s[r];
  const float* src = B_pool + (size_t)e * OUT_ * R_ + r;
  float* dst = loraBp + (size_t)(b * R_ + r) * OUT_;
  #pragma unroll
  for (int i = 0; i < 16; ++i) {
    const int o = i * 256 + tid;
    dst[o] = src[(size_t)o * R_];
  }
}

// ---------------- K4: out = (reduced after_A) @ lora_Bp ----------------------
// grid 2048 = b(8) x st(64 tiles of 32 rows) x oc(4): 8 blocks/CU. (R11 body)
__global__ __launch_bounds__(256) void k_out(
    const float* __restrict__ partial, const float* __restrict__ loraBp,
    float* __restrict__ out)
{
  const int bx = blockIdx.x;
  const int oc = bx & 3, st = (bx >> 2) & 63, b = bx >> 8;
  __shared__ float aa[32][R_];   // 2 KB
  const int tid = threadIdx.x;
  if (tid < 128) {
    // 64-row tile rt = st>>1 holds the 8 ks-slabs; take half of each slab
    const float* base = partial + (((size_t)(b * 32 + (st >> 1)) * 8) << 10)
                        + (st & 1) * 512 + tid * 4;
    float4 s = ntload4(base);
    #pragma unroll
    for (int k = 1; k < 8; ++k) {
      float4 t = ntload4(base + k * 1024);
      s.x += t.x; s.y += t.y; s.z += t.z; s.w += t.w;
    }
    ((float4*)aa)[tid] = s;
  }
  float4 Bf[R_];
  #pragma unroll
  for (int r = 0; r < R_; ++r)
    Bf[r] = *(const float4*)(loraBp + (size_t)(b * R_ + r) * OUT_ + oc * 1024 + tid * 4);
  __syncthreads();
  const int row0 = st * 32;
  float* obase = out + ((size_t)b * S_ + row0) * OUT_ + oc * 1024 + tid * 4;
  #pragma unroll 2
  for (int s = 0; s < 32; ++s) {
    const float4* av = (const float4*)aa[s];
    float4 a0 = av[0], a1 = av[1], a2 = av[2], a3 = av[3];
    float4 o = make_float4(0.f, 0.f, 0.f, 0.f);
    o.x += a0.x*Bf[0].x;  o.y += a0.x*Bf[0].y;  o.z += a0.x*Bf[0].z;  o.w += a0.x*Bf[0].w;
    o.x += a0.y*Bf[1].x;  o.y += a0.y*Bf[1].y;  o.z += a0.y*Bf[1].z;  o.w += a0.y*Bf[1].w;
    o.x += a0.z*Bf[2].x;  o.y += a0.z*Bf[2].y;  o.z += a0.z*Bf[2].z;  o.w += a0.z*Bf[2].w;
    o.x += a0.w*Bf[3].x;  o.y += a0.w*Bf[3].y;  o.z += a0.w*Bf[3].z;  o.w += a0.w*Bf[3].w;
    o.x += a1.x*Bf[4].x;  o.y += a1.x*Bf[4].y;  o.z += a1.x*Bf[4].z;  o.w += a1.x*Bf[4].w;
    o.x += a1.y*Bf[5].x;  o.y += a1.y*Bf[5].y;  o.z += a1.y*Bf[5].z;  o.w += a1.y*Bf[5].w;
    o.x += a1.z*Bf[6].x;  o.y += a1.z*Bf[6].y;  o.z += a1.z*Bf[6].z;  o.w += a1.z*Bf[6].w;
    o.x += a1.w*Bf[7].x;  o.y += a1.w*Bf[7].y;  o.z += a1.w*Bf[7].z;  o.w += a1.w*Bf[7].w;
    o.x += a2.x*Bf[8].x;  o.y += a2.x*Bf[8].y;  o.z += a2.x*Bf[8].z;  o.w += a2.x*Bf[8].w;
    o.x += a2.y*Bf[9].x;  o.y += a2.y*Bf[9].y;  o.z += a2.y*Bf[9].z;  o.w += a2.y*Bf[9].w;
    o.x += a2.z*Bf[10].x; o.y += a2.z*Bf[10].y; o.z += a2.z*Bf[10].z; o.w += a2.z*Bf[10].w;
    o.x += a2.w*Bf[11].x; o.y += a2.w*Bf[11].y; o.z += a2.w*Bf[11].z; o.w += a2.w*Bf[11].w;
    o.x += a3.x*Bf[12].x; o.y += a3.x*Bf[12].y; o.z += a3.x*Bf[12].z; o.w += a3.x*Bf[12].w;
    o.x += a3.y*Bf[13].x; o.y += a3.y*Bf[13].y; o.z += a3.y*Bf[13].z; o.w += a3.y*Bf[13].w;
    o.x += a3.z*Bf[14].x; o.y += a3.z*Bf[14].y; o.z += a3.z*Bf[14].z; o.w += a3.z*Bf[14].w;
    o.x += a3.w*Bf[15].x; o.y += a3.w*Bf[15].y; o.z += a3.w*Bf[15].z; o.w += a3.w*Bf[15].w;
    ntstore4(obase + (size_t)s * OUT_, o);
  }
}

// ---------------- launch ------------------------------------------------------
extern "C" void kernel_launch(void* const* d_in, const int* in_sizes, int n_in,
                              void* d_out, int out_size, void* d_ws, size_t ws_size,
                              hipStream_t stream) {
  const float* x      = (const float*)d_in[0];
  const float* qsig   = (const float*)d_in[1];
  const float* A_pool = (const float*)d_in[2];
  const float* B_pool = (const float*)d_in[3];
  const float* W_rA   = (const float*)d_in[4];
  const float* b_rA   = (const float*)d_in[5];
  const float* W_rB   = (const float*)d_in[6];
  const float* b_rB   = (const float*)d_in[7];
  const float* cfs_W  = (const float*)d_in[8];
  float* out = (float*)d_out;

  char* w = (char*)d_ws;
  int*   idxA    = (int*)(w);               // 512 B
  float* sApart  = (float*)(w + 1024);      // 8 KB
  float* gApart  = (float*)(w + 9216);      // 8 KB
  float* gB0     = (float*)(w + 17408);     // 2 KB
  float* gBpart  = (float*)(w + 19456);     // 128*8*64*4 = 256 KB
  float* loraBp  = (float*)(w + 281600);    // 8*16*4096*4 = 2 MB
  float* partial = (float*)(w + 2378752);   // 8*32*8*4096 B = 8 MB (ends ~10.7 MB)

  k_scores<<<256, 256, 0, stream>>>(qsig, W_rA, W_rB, sApart, gApart);
  k_topk_a<<<8, 64, 0, stream>>>(sApart, gApart, b_rA, b_rB, gB0, idxA);
  k_fused_ac<<<2176, 256, 0, stream>>>(x, A_pool, idxA, cfs_W, gBpart, partial);
  k_topkb_pack<<<128, 256, 0, stream>>>(gB0, gBpart, B_pool, loraBp);
  k_out<<<2048, 256, 0, stream>>>(partial, loraBp, out);
}

// Round 19
// 174.984 us; speedup vs baseline: 1.5871x; 1.5871x over previous
//
#include <hip/hip_runtime.h>

#define B_ 8
#define S_ 2048
#define IN_ 4096
#define OUT_ 4096
#define R_ 16
#define E_ 64

typedef float v4f __attribute__((ext_vector_type(4)));

__device__ __forceinline__ float4 ntload4(const float* p) {
  v4f t = __builtin_nontemporal_load((const v4f*)p);
  float4 r; r.x = t.x; r.y = t.y; r.z = t.z; r.w = t.w; return r;
}
__device__ __forceinline__ void ntstore4(float* p, float4 v) {
  v4f t; t.x = v.x; t.y = v.y; t.z = v.z; t.w = v.w;
  __builtin_nontemporal_store(t, (v4f*)p);
}

__device__ __forceinline__ float dot4(float4 a, float4 b) {
  return a.x*b.x + a.y*b.y + a.z*b.z + a.w*b.w;
}

// wave-parallel top-16 (descending, ties -> lower index, matching lax.top_k)
__device__ __forceinline__ void topk16(float v, int* __restrict__ dst) {
  const int lane = threadIdx.x & 63;
  for (int r = 0; r < R_; ++r) {
    float mv = v; int mi = lane;
    #pragma unroll
    for (int off = 1; off < 64; off <<= 1) {
      float v2 = __shfl_xor(mv, off, 64);
      int   i2 = __shfl_xor(mi, off, 64);
      if (v2 > mv || (v2 == mv && i2 < mi)) { mv = v2; mi = i2; }
    }
    if (lane == 0) dst[r] = mi;
    if (lane == mi) v = -__builtin_inff();
  }
}

// ---------------- K1: score partial dots (256 blocks = b x eg x ic) ----------
__global__ __launch_bounds__(256) void k_scores(
    const float* __restrict__ q, const float* __restrict__ W_rA,
    const float* __restrict__ W_rB, float* __restrict__ sApart,
    float* __restrict__ gApart)
{
  const int bx = blockIdx.x;
  const int b = bx >> 5, eg = (bx >> 2) & 7, ic = bx & 3;
  __shared__ float qs[1024];
  const int tid = threadIdx.x;
  {
    const float4* q4 = (const float4*)(q + (size_t)b * IN_ + ic * 1024);
    ((float4*)qs)[tid] = q4[tid];
  }
  __syncthreads();
  const int wave = tid >> 6, lane = tid & 63;
  const float4* qs4 = (const float4*)qs;
  #pragma unroll
  for (int k = 0; k < 2; ++k) {
    const int e = eg * 8 + wave * 2 + k;
    const float4* wa = (const float4*)(W_rA + (size_t)e * IN_ + ic * 1024);
    const float4* wb = (const float4*)(W_rB + (size_t)e * IN_ + ic * 1024);
    float pa = 0.f, pb = 0.f;
    #pragma unroll
    for (int i = 0; i < 4; ++i) {
      float4 qv = qs4[lane + i * 64];
      pa += dot4(qv, wa[lane + i * 64]);
      pb += dot4(qv, wb[lane + i * 64]);
    }
    #pragma unroll
    for (int off = 1; off < 64; off <<= 1) {
      pa += __shfl_xor(pa, off, 64);
      pb += __shfl_xor(pb, off, 64);
    }
    if (lane == 0) {
      sApart[(ic * B_ + b) * E_ + e] = pa;
      gApart[(ic * B_ + b) * E_ + e] = pb;
    }
  }
}

// ---------------- K1b: reduce partials, bias, topk_A, final gB0 --------------
__global__ __launch_bounds__(64) void k_topk_a(
    const float* __restrict__ sApart, const float* __restrict__ gApart,
    const float* __restrict__ b_rA, const float* __restrict__ b_rB,
    float* __restrict__ gB0, int* __restrict__ idxA)
{
  const int b = blockIdx.x;
  const int e = threadIdx.x & 63;
  float sA = b_rA[e], g = b_rB[e];
  #pragma unroll
  for (int ic = 0; ic < 4; ++ic) {
    sA += sApart[(ic * B_ + b) * E_ + e];
    g  += gApart[(ic * B_ + b) * E_ + e];
  }
  gB0[b * E_ + e] = g;
  topk16(sA, idxA + b * R_);
}

// ---------------- K2: fused [cfs (blocks 0-127) | after_A (blocks 128-2175)] --
// cfs: 128 units = r(16) x ic(8), reads cfs_W exactly once, writes gBpart.
// after: 2048 units = ks(8) x b(8) x rt(32 tiles of 64 rows), writes partial
//        as block-contiguous 4 KB tiles [(b*32+rt)*8 + ks].
// NOTE: R11-proven body. Do NOT cap waves (R18: __launch_bounds__(256,5)
// forced VGPR 48 -> acc spill, 392 MB scratch traffic, 180 us). Do NOT
// manually unroll the load loop (R10: VGPR 256 spill). acc[4][16] = 64 VGPR
// floor means 4 waves/SIMD is this body's occupancy ceiling.
__global__ __launch_bounds__(256) void k_fused_ac(
    const float* __restrict__ x, const float* __restrict__ A_pool,
    const int* __restrict__ idxA, const float* __restrict__ cfs,
    float* __restrict__ gBpart, float* __restrict__ partial)
{
  __shared__ union {
    struct { float4 As[R_][128]; float aa[64][R_]; } a;   // 36 KB
    struct { float as[B_][512]; float red[4][B_][E_]; } c; // 24 KB
  } sm;
  const int tid = threadIdx.x;

  if (blockIdx.x < 128) {
    // ---------------- cfs einsum partials ----------------
    const int blk = blockIdx.x;
    const int r = blk >> 3, ic = blk & 7;
    {
      const int b = tid >> 5, t = tid & 31;
      const int e = idxA[b * R_ + r];
      const float4* src = (const float4*)(A_pool + ((size_t)e * R_ + r) * IN_ + ic * 512);
      float4* dst = (float4*)sm.c.as[b];
      for (int j = t; j < 128; j += 32) dst[j] = src[j];
    }
    __syncthreads();
    const int e = tid & 63, part = tid >> 6;
    float acc[B_];
    #pragma unroll
    for (int b = 0; b < B_; ++b) acc[b] = 0.f;
    const float* cbase = cfs + ((size_t)r * IN_ + ic * 512) * E_ + e;
    for (int i = part * 128; i < part * 128 + 128; ++i) {
      float c = __builtin_nontemporal_load(cbase + (size_t)i * E_);
      #pragma unroll
      for (int b = 0; b < B_; ++b) acc[b] += sm.c.as[b][i] * c;
    }
    #pragma unroll
    for (int b = 0; b < B_; ++b) sm.c.red[part][b][e] = acc[b];
    __syncthreads();
    if (tid < 64) {
      #pragma unroll
      for (int b = 0; b < B_; ++b)
        gBpart[((size_t)blk * B_ + b) * E_ + tid] =
            sm.c.red[0][b][tid] + sm.c.red[1][b][tid] +
            sm.c.red[2][b][tid] + sm.c.red[3][b][tid];
    }
    return;
  }

  // ---------------- after_A split-K (R9/R11 proven body) ----------------
  const int bx = blockIdx.x - 128;
  const int rt = bx & 31, b = (bx >> 5) & 7, ks = bx >> 8;
  const int row0 = rt * 64;
  {
    const int sr = tid >> 4, st = tid & 15;
    const float4* src =
        (const float4*)(A_pool + ((size_t)idxA[b * R_ + sr] * R_ + sr) * IN_ + ks * 512);
    #pragma unroll
    for (int j = st; j < 128; j += 16) sm.a.As[sr][j] = src[j];
  }
  const int rg = tid >> 4, p = tid & 15;  // rows rg*4..rg*4+3, 16-way i4 split
  const float* xbase = x + ((size_t)b * S_ + row0 + rg * 4) * IN_ + ks * 512;
  float acc[4][R_];
  #pragma unroll
  for (int m = 0; m < 4; ++m)
    #pragma unroll
    for (int r = 0; r < R_; ++r) acc[m][r] = 0.f;
  __syncthreads();

  #pragma unroll 2
  for (int step = 0; step < 8; ++step) {
    const int i4 = step * 16 + p;
    float4 xv[4];
    #pragma unroll
    for (int m = 0; m < 4; ++m)
      xv[m] = ntload4(xbase + (size_t)m * IN_ + i4 * 4);
    #pragma unroll
    for (int r = 0; r < R_; ++r) {
      float4 a = sm.a.As[r][i4];
      #pragma unroll
      for (int m = 0; m < 4; ++m) acc[m][r] += dot4(xv[m], a);
    }
  }
  // reduce across the 16 p-lanes (bits 0..3 of lane)
  #pragma unroll
  for (int m = 0; m < 4; ++m)
    #pragma unroll
    for (int r = 0; r < R_; ++r) {
      float v = acc[m][r];
      v += __shfl_xor(v, 1, 64);
      v += __shfl_xor(v, 2, 64);
      v += __shfl_xor(v, 4, 64);
      v += __shfl_xor(v, 8, 64);
      acc[m][r] = v;
    }
  if (p == 0) {
    #pragma unroll
    for (int m = 0; m < 4; ++m) {
      float4* d4 = (float4*)sm.a.aa[rg * 4 + m];
      d4[0] = make_float4(acc[m][0],  acc[m][1],  acc[m][2],  acc[m][3]);
      d4[1] = make_float4(acc[m][4],  acc[m][5],  acc[m][6],  acc[m][7]);
      d4[2] = make_float4(acc[m][8],  acc[m][9],  acc[m][10], acc[m][11]);
      d4[3] = make_float4(acc[m][12], acc[m][13], acc[m][14], acc[m][15]);
    }
  }
  __syncthreads();
  // coalesced nt 4 KB tile store
  float4 w = ((const float4*)sm.a.aa)[tid];
  ntstore4(partial + (((size_t)(b * 32 + rt) * 8 + ks) << 10) + tid * 4, w);
}

// ---------------- K3: topk_B + pack lora_B fused ------------------------------
// grid 128 = b(8) x r(16). Wave-split reduction over 128 gBpart blocks.
__global__ __launch_bounds__(256) void k_topkb_pack(
    const float* __restrict__ gB0, const float* __restrict__ gBpart,
    const float* __restrict__ B_pool, float* __restrict__ loraBp)
{
  const int b = blockIdx.x >> 4, r = blockIdx.x & 15;
  __shared__ float red[4][E_];
  __shared__ int idxB_s[R_];
  const int tid = threadIdx.x;
  const int wave = tid >> 6, lane = tid & 63;
  float p = 0.f;
  for (int blk = wave * 32; blk < wave * 32 + 32; ++blk)
    p += gBpart[((size_t)blk * B_ + b) * E_ + lane];
  red[wave][lane] = p;
  __syncthreads();
  if (wave == 0) {
    float v = gB0[b * E_ + lane] + red[0][lane] + red[1][lane] + red[2][lane] + red[3][lane];
    topk16(v, idxB_s);
  }
  __syncthreads();
  const int e = idxB_s[r];
  const float* src = B_pool + (size_t)e * OUT_ * R_ + r;
  float* dst = loraBp + (size_t)(b * R_ + r) * OUT_;
  #pragma unroll
  for (int i = 0; i < 16; ++i) {
    const int o = i * 256 + tid;
    dst[o] = src[(size_t)o * R_];
  }
}

// ---------------- K4: out = (reduced after_A) @ lora_Bp ----------------------
// grid 2048 = b(8) x st(64 tiles of 32 rows) x oc(4): 8 blocks/CU.
__global__ __launch_bounds__(256) void k_out(
    const float* __restrict__ partial, const float* __restrict__ loraBp,
    float* __restrict__ out)
{
  const int bx = blockIdx.x;
  const int oc = bx & 3, st = (bx >> 2) & 63, b = bx >> 8;
  __shared__ float aa[32][R_];   // 2 KB
  const int tid = threadIdx.x;
  if (tid < 128) {
    // 64-row tile rt = st>>1 holds the 8 ks-slabs; take half of each slab
    const float* base = partial + (((size_t)(b * 32 + (st >> 1)) * 8) << 10)
                        + (st & 1) * 512 + tid * 4;
    float4 s = ntload4(base);
    #pragma unroll
    for (int k = 1; k < 8; ++k) {
      float4 t = ntload4(base + k * 1024);
      s.x += t.x; s.y += t.y; s.z += t.z; s.w += t.w;
    }
    ((float4*)aa)[tid] = s;
  }
  float4 Bf[R_];
  #pragma unroll
  for (int r = 0; r < R_; ++r)
    Bf[r] = *(const float4*)(loraBp + (size_t)(b * R_ + r) * OUT_ + oc * 1024 + tid * 4);
  __syncthreads();
  const int row0 = st * 32;
  float* obase = out + ((size_t)b * S_ + row0) * OUT_ + oc * 1024 + tid * 4;
  #pragma unroll 2
  for (int s = 0; s < 32; ++s) {
    const float4* av = (const float4*)aa[s];
    float4 a0 = av[0], a1 = av[1], a2 = av[2], a3 = av[3];
    float4 o = make_float4(0.f, 0.f, 0.f, 0.f);
    o.x += a0.x*Bf[0].x;  o.y += a0.x*Bf[0].y;  o.z += a0.x*Bf[0].z;  o.w += a0.x*Bf[0].w;
    o.x += a0.y*Bf[1].x;  o.y += a0.y*Bf[1].y;  o.z += a0.y*Bf[1].z;  o.w += a0.y*Bf[1].w;
    o.x += a0.z*Bf[2].x;  o.y += a0.z*Bf[2].y;  o.z += a0.z*Bf[2].z;  o.w += a0.z*Bf[2].w;
    o.x += a0.w*Bf[3].x;  o.y += a0.w*Bf[3].y;  o.z += a0.w*Bf[3].z;  o.w += a0.w*Bf[3].w;
    o.x += a1.x*Bf[4].x;  o.y += a1.x*Bf[4].y;  o.z += a1.x*Bf[4].z;  o.w += a1.x*Bf[4].w;
    o.x += a1.y*Bf[5].x;  o.y += a1.y*Bf[5].y;  o.z += a1.y*Bf[5].z;  o.w += a1.y*Bf[5].w;
    o.x += a1.z*Bf[6].x;  o.y += a1.z*Bf[6].y;  o.z += a1.z*Bf[6].z;  o.w += a1.z*Bf[6].w;
    o.x += a1.w*Bf[7].x;  o.y += a1.w*Bf[7].y;  o.z += a1.w*Bf[7].z;  o.w += a1.w*Bf[7].w;
    o.x += a2.x*Bf[8].x;  o.y += a2.x*Bf[8].y;  o.z += a2.x*Bf[8].z;  o.w += a2.x*Bf[8].w;
    o.x += a2.y*Bf[9].x;  o.y += a2.y*Bf[9].y;  o.z += a2.y*Bf[9].z;  o.w += a2.y*Bf[9].w;
    o.x += a2.z*Bf[10].x; o.y += a2.z*Bf[10].y; o.z += a2.z*Bf[10].z; o.w += a2.z*Bf[10].w;
    o.x += a2.w*Bf[11].x; o.y += a2.w*Bf[11].y; o.z += a2.w*Bf[11].z; o.w += a2.w*Bf[11].w;
    o.x += a3.x*Bf[12].x; o.y += a3.x*Bf[12].y; o.z += a3.x*Bf[12].z; o.w += a3.x*Bf[12].w;
    o.x += a3.y*Bf[13].x; o.y += a3.y*Bf[13].y; o.z += a3.y*Bf[13].z; o.w += a3.y*Bf[13].w;
    o.x += a3.z*Bf[14].x; o.y += a3.z*Bf[14].y; o.z += a3.z*Bf[14].z; o.w += a3.z*Bf[14].w;
    o.x += a3.w*Bf[15].x; o.y += a3.w*Bf[15].y; o.z += a3.w*Bf[15].z; o.w += a3.w*Bf[15].w;
    ntstore4(obase + (size_t)s * OUT_, o);
  }
}

// ---------------- launch ------------------------------------------------------
extern "C" void kernel_launch(void* const* d_in, const int* in_sizes, int n_in,
                              void* d_out, int out_size, void* d_ws, size_t ws_size,
                              hipStream_t stream) {
  const float* x      = (const float*)d_in[0];
  const float* qsig   = (const float*)d_in[1];
  const float* A_pool = (const float*)d_in[2];
  const float* B_pool = (const float*)d_in[3];
  const float* W_rA   = (const float*)d_in[4];
  const float* b_rA   = (const float*)d_in[5];
  const float* W_rB   = (const float*)d_in[6];
  const float* b_rB   = (const float*)d_in[7];
  const float* cfs_W  = (const float*)d_in[8];
  float* out = (float*)d_out;

  char* w = (char*)d_ws;
  int*   idxA    = (int*)(w);               // 512 B
  float* sApart  = (float*)(w + 1024);      // 8 KB
  float* gApart  = (float*)(w + 9216);      // 8 KB
  float* gB0     = (float*)(w + 17408);     // 2 KB
  float* gBpart  = (float*)(w + 19456);     // 128*8*64*4 = 256 KB
  float* loraBp  = (float*)(w + 281600);    // 8*16*4096*4 = 2 MB
  float* partial = (float*)(w + 2378752);   // 8*32*8*4096 B = 8 MB (ends ~10.7 MB)

  k_scores<<<256, 256, 0, stream>>>(qsig, W_rA, W_rB, sApart, gApart);
  k_topk_a<<<8, 64, 0, stream>>>(sApart, gApart, b_rA, b_rB, gB0, idxA);
  k_fused_ac<<<2176, 256, 0, stream>>>(x, A_pool, idxA, cfs_W, gBpart, partial);
  k_topkb_pack<<<128, 256, 0, stream>>>(gB0, gBpart, B_pool, loraBp);
  k_out<<<2048, 256, 0, stream>>>(partial, loraBp, out);
}